// Round 5
// baseline (186.208 us; speedup 1.0000x reference)
//
#include <hip/hip_runtime.h>

#pragma clang fp contract(off)

#define A_TOTAL 65472
#define NB 16
#define NG 32
#define NLVL 5

// level boundaries (cumulative): 49152, 61440, 64512, 65280, 65472

__device__ __forceinline__ float iou_f(float ax1, float ay1, float ax2, float ay2,
                                       float gx1, float gy1, float gx2, float gy2) {
    float x1 = fmaxf(ax1, gx1);
    float y1 = fmaxf(ay1, gy1);
    float x2 = fminf(ax2, gx2);
    float y2 = fminf(ay2, gy2);
    float w = fmaxf(x2 - x1, 0.0f);
    float h = fmaxf(y2 - y1, 0.0f);
    float inter = w * h;
    float aa = (ax2 - ax1) * (ay2 - ay1);
    float ag = (gx2 - gx1) * (gy2 - gy1);
    float denom = aa + ag - inter + 1e-9f;
    return inter / denom;
}

// Pass 1: one block per (b,g). Computes, per level, max IoU over that level's
// anchors and the FIRST argmax anchor (global index). Then picks the level with
// the (first) max over levels and stores the forced anchor global index.
__global__ __launch_bounds__(256) void pass1_kernel(
    const float* __restrict__ bb,      // [NB][NG][4]
    const float* __restrict__ anchors, // [A_TOTAL][4]
    int* __restrict__ forced)          // [NB][NG] -> global anchor idx
{
    const int bg = blockIdx.x;
    const int b = bg >> 5;
    const int g = bg & 31;
    const int t = threadIdx.x;

    const float4 gt = ((const float4*)bb)[b * NG + g];

    float mv[NLVL];
    int   ma[NLVL];
#pragma unroll
    for (int l = 0; l < NLVL; ++l) { mv[l] = -1.0f; ma[l] = 0x7fffffff; }

    for (int n = t; n < A_TOTAL; n += 256) {
        float4 an = ((const float4*)anchors)[n];
        float v = iou_f(an.x, an.y, an.z, an.w, gt.x, gt.y, gt.z, gt.w);
        int l = (n < 49152) ? 0 : (n < 61440) ? 1 : (n < 64512) ? 2 : (n < 65280) ? 3 : 4;
        // ascending n per thread: strict > keeps first argmax
        if (v > mv[l]) { mv[l] = v; ma[l] = n; }
    }

    __shared__ float smax[NLVL][256];
    __shared__ int   sarg[NLVL][256];
#pragma unroll
    for (int l = 0; l < NLVL; ++l) { smax[l][t] = mv[l]; sarg[l][t] = ma[l]; }
    __syncthreads();

    for (int s = 128; s > 0; s >>= 1) {
        if (t < s) {
#pragma unroll
            for (int l = 0; l < NLVL; ++l) {
                float v2 = smax[l][t + s];
                int   a2 = sarg[l][t + s];
                float v1 = smax[l][t];
                int   a1 = sarg[l][t];
                if (v2 > v1 || (v2 == v1 && a2 < a1)) { smax[l][t] = v2; sarg[l][t] = a2; }
            }
        }
        __syncthreads();
    }

    if (t == 0) {
        float best = smax[0][0];
        int bl = 0;
#pragma unroll
        for (int l = 1; l < NLVL; ++l) {
            if (smax[l][0] > best) { best = smax[l][0]; bl = l; }  // first max over levels
        }
        forced[b * NG + g] = sarg[bl][0];
    }
}

// Pass 2: one thread per (b, n). Computes max IoU over GTs (first argmax),
// checks forced list (last g wins), emits label (as float) + regs.
__global__ __launch_bounds__(256) void pass2_kernel(
    const float* __restrict__ bb,      // [NB][NG][4]
    const int* __restrict__ ids,       // [NB][NG]
    const float* __restrict__ anchors, // [A_TOTAL][4]
    const int* __restrict__ forced,    // [NB][NG]
    float* __restrict__ out)           // labels [NB*A_TOTAL] then regs [NB*A_TOTAL*4]
{
    const int b = blockIdx.x >> 8;          // 256 blocks per batch image
    const int chunk = blockIdx.x & 255;
    const int n = chunk * 256 + threadIdx.x;

    __shared__ float4 sbb[NG];
    __shared__ int sid[NG];
    __shared__ int sfor[NG];
    if (threadIdx.x < NG) {
        sbb[threadIdx.x] = ((const float4*)bb)[b * NG + threadIdx.x];
        sid[threadIdx.x] = ids[b * NG + threadIdx.x];
        sfor[threadIdx.x] = forced[b * NG + threadIdx.x];
    }
    __syncthreads();
    if (n >= A_TOTAL) return;

    const float4 an = ((const float4*)anchors)[n];

    float best = -1.0f;
    int bestg = 0;
#pragma unroll
    for (int g = 0; g < NG; ++g) {
        float4 q = sbb[g];
        float v = iou_f(an.x, an.y, an.z, an.w, q.x, q.y, q.z, q.w);
        if (v > best) { best = v; bestg = g; }  // first argmax over g
    }

    int fg = -1;
#pragma unroll
    for (int g = 0; g < NG; ++g) {
        if (sfor[g] == n) fg = g;  // last g wins (scatter overwrite semantics)
    }

    float label;
    float4 r;
    const bool pos = (best >= 0.5f) || (fg >= 0);
    if (pos) {
        const int gg = (fg >= 0) ? fg : bestg;
        const float4 gtb = sbb[gg];
        label = (float)sid[gg];
        float aw = an.z - an.x;
        float ah = an.w - an.y;
        float ax = an.x + 0.5f * aw;
        float ay = an.y + 0.5f * ah;
        float gw = gtb.z - gtb.x;
        float gh = gtb.w - gtb.y;
        float gx = gtb.x + 0.5f * gw;
        float gy = gtb.y + 0.5f * gh;
        r = make_float4((gx - ax) / aw, (gy - ay) / ah, logf(gw / aw), logf(gh / ah));
    } else {
        label = (best >= 0.4f) ? -1.0f : 0.0f;
        r = make_float4(0.0f, 0.0f, 0.0f, 0.0f);
    }

    out[b * A_TOTAL + n] = label;
    ((float4*)(out + NB * A_TOTAL))[b * A_TOTAL + n] = r;
}

extern "C" void kernel_launch(void* const* d_in, const int* in_sizes, int n_in,
                              void* d_out, int out_size, void* d_ws, size_t ws_size,
                              hipStream_t stream) {
    const float* bb      = (const float*)d_in[0];   // bb_coord [16][32][4] f32
    const int*   ids     = (const int*)d_in[1];     // bird_ids [16][32] i32
    const float* anchors = (const float*)d_in[2];   // anchors [65472][4] f32
    float* out = (float*)d_out;
    int* forced = (int*)d_ws;                       // [16][32] ints

    hipLaunchKernelGGL(pass1_kernel, dim3(NB * NG), dim3(256), 0, stream,
                       bb, anchors, forced);
    hipLaunchKernelGGL(pass2_kernel, dim3(NB * 256), dim3(256), 0, stream,
                       bb, ids, anchors, forced, out);
}